// Round 1
// baseline (176.914 us; speedup 1.0000x reference)
//
#include <hip/hip_runtime.h>
#include <math.h>

#define N_ROWS 32768
#define KCODES 1024
#define DIM 64
#define OUT_Q 1
#define Q_ELEMS 2097152
#define OUT_PERP 2097153
#define OUT_ENC 2097154
#define MARGIN 2e-5f

// ---------------------------------------------------------------------------
// Kernel P0: sqnorm_half[k] = 0.5 * ||e_k||^2  (fp64 accumulate, store fp32)
// ---------------------------------------------------------------------------
__global__ void vq_sqnorm_kernel(const float* __restrict__ emb,
                                 float* __restrict__ sqnh) {
    int k = blockIdx.x * blockDim.x + threadIdx.x;  // 1024 threads
    const float4* e4 = (const float4*)(emb + k * DIM);
    double s = 0.0;
#pragma unroll
    for (int q = 0; q < 16; ++q) {
        float4 v = e4[q];
        s += (double)v.x * v.x + (double)v.y * v.y +
             (double)v.z * v.z + (double)v.w * v.w;
    }
    sqnh[k] = (float)(0.5 * s);
}

// ---------------------------------------------------------------------------
// Kernel A: fp32 argmin scan. Each lane owns one row (x in 64 VGPRs); waves
// split the K range. dist' = 0.5*||e||^2 - x.e (monotone-equal to reference).
// Tracks best AND second-best for the fp64 recheck margin test.
// blockIdx: rowgroup = b / ks, khalf = b % ks. Grid = 512*ks blocks x 256.
// ---------------------------------------------------------------------------
__global__ __launch_bounds__(256) void vq_argmin_kernel(
    const float* __restrict__ x, const float* __restrict__ emb,
    const float* __restrict__ sqnh,
    float* __restrict__ bestA, float* __restrict__ secA,
    int* __restrict__ idxA, int ks) {
    int lane = threadIdx.x & 63;
    int wave = __builtin_amdgcn_readfirstlane(threadIdx.x >> 6);
    int half = blockIdx.x % ks;
    int rowgroup = blockIdx.x / ks;
    int n = rowgroup * 64 + lane;
    int kspan = KCODES / ks;   // 512 (ks=2) or 1024 (ks=1)
    int cpw = kspan >> 2;      // codes per wave: 128 or 256
    int k0 = half * kspan + wave * cpw;

    // load this lane's row: stride-4096 element loads, coalesced across lanes
    const float* xp = x + ((n >> 12) * 262144 + (n & 4095));
    float xv[DIM];
#pragma unroll
    for (int d = 0; d < DIM; ++d) xv[d] = xp[d * 4096];

    float best = 1e30f, second = 1e30f;
    int bi = 0;
    const float* ep = emb + (size_t)k0 * DIM;
    for (int kk = 0; kk < cpw; ++kk) {
        // e row address is wave-uniform -> s_load; 4 accumulators for ILP
        float a0 = 0.f, a1 = 0.f, a2 = 0.f, a3 = 0.f;
#pragma unroll
        for (int d = 0; d < DIM; d += 4) {
            a0 = fmaf(ep[d + 0], xv[d + 0], a0);
            a1 = fmaf(ep[d + 1], xv[d + 1], a1);
            a2 = fmaf(ep[d + 2], xv[d + 2], a2);
            a3 = fmaf(ep[d + 3], xv[d + 3], a3);
        }
        float dist = sqnh[k0 + kk] - ((a0 + a1) + (a2 + a3));
        bool lt = dist < best;           // strict: keeps lowest index on ties
        second = lt ? best : fminf(second, dist);
        bi = lt ? (k0 + kk) : bi;
        best = lt ? dist : best;
        ep += DIM;
    }

    // cross-wave (k-chunk) merge within the block
    __shared__ float sb[4][64], ss[4][64];
    __shared__ int si[4][64];
    sb[wave][lane] = best; ss[wave][lane] = second; si[wave][lane] = bi;
    __syncthreads();
    if (wave == 0) {
        float b = sb[0][lane], s2 = ss[0][lane];
        int ix = si[0][lane];
        for (int w = 1; w < 4; ++w) {
            float bw = sb[w][lane], sw = ss[w][lane];
            int iw = si[w][lane];
            if (bw < b) { s2 = fminf(b, sw); b = bw; ix = iw; }
            else        { s2 = fminf(s2, bw); }
        }
        bestA[half * N_ROWS + n] = b;
        secA[half * N_ROWS + n] = s2;
        idxA[half * N_ROWS + n] = ix;
    }
}

// ---------------------------------------------------------------------------
// Kernel M: merge K-halves, write idx, flag rows whose fp32 gap < MARGIN.
// ---------------------------------------------------------------------------
__global__ void vq_merge_kernel(const float* __restrict__ bestA,
                                const float* __restrict__ secA,
                                const int* __restrict__ idxA, int ks,
                                int* __restrict__ idxp,
                                int* __restrict__ flaglist,
                                int* __restrict__ flagcount) {
    int n = blockIdx.x * blockDim.x + threadIdx.x;  // 32768 threads
    float b = bestA[n], s2 = secA[n];
    int ix = idxA[n];
    if (ks == 2) {
        float b1 = bestA[N_ROWS + n], s1 = secA[N_ROWS + n];
        int i1 = idxA[N_ROWS + n];
        if (b1 < b) { s2 = fminf(b, s1); b = b1; ix = i1; }
        else        { s2 = fminf(s2, b1); }
    }
    idxp[n] = ix;
    if (s2 - b < MARGIN) {
        int pos = atomicAdd(flagcount, 1);
        flaglist[pos] = n;
    }
}

// ---------------------------------------------------------------------------
// Kernel B: exact fp64 re-scan of flagged rows. One wave per row:
// lane = (kgrp<<2)|dgrp; dgrp covers 16 of D, kgrp covers 64 of K.
// ---------------------------------------------------------------------------
__global__ __launch_bounds__(256) void vq_recheck_kernel(
    const float* __restrict__ x, const float* __restrict__ emb,
    const int* __restrict__ flaglist, const int* __restrict__ flagcount,
    int* __restrict__ idxp) {
    int lane = threadIdx.x & 63;
    int gw = (blockIdx.x * blockDim.x + threadIdx.x) >> 6;  // 0..1023
    int nf = flagcount[0];
    int dg = lane & 3, kg = lane >> 2;
    for (int i = gw; i < nf; i += 1024) {
        int n = flaglist[i];
        const float* xp = x + ((n >> 12) * 262144 + (n & 4095) + dg * 16 * 4096);
        double xd[16];
#pragma unroll
        for (int j = 0; j < 16; ++j) xd[j] = (double)xp[j * 4096];
        double best = 1e300;
        int bi = 0;
        for (int j = 0; j < 64; ++j) {
            int k = kg * 64 + j;  // ascending within group
            const float4* e4 = (const float4*)(emb + k * DIM + dg * 16);
            double u = 0.0;
#pragma unroll
            for (int q = 0; q < 4; ++q) {
                float4 ev = e4[q];
                double e0 = ev.x, e1 = ev.y, e2 = ev.z, e3 = ev.w;
                u += e0 * (0.5 * e0 - xd[q * 4 + 0]);
                u += e1 * (0.5 * e1 - xd[q * 4 + 1]);
                u += e2 * (0.5 * e2 - xd[q * 4 + 2]);
                u += e3 * (0.5 * e3 - xd[q * 4 + 3]);
            }
            u += __shfl_xor(u, 1);   // reduce across the 4 dgrp lanes
            u += __shfl_xor(u, 2);
            if (u < best) { best = u; bi = k; }
        }
        // merge across 16 kgrp leaders (offsets are multiples of 4; own value
        // is the lower k-group -> strict < keeps lowest index on ties)
        for (int off = 4; off < 64; off <<= 1) {
            double ob = __shfl_down(best, off);
            int oi = __shfl_down(bi, off);
            if (ob < best) { best = ob; bi = oi; }
        }
        if (lane == 0) idxp[n] = bi;
    }
}

// ---------------------------------------------------------------------------
// Kernel C: gather quantized (NCHW), loss partials, counts, encodings.
// Phase 1: wave w owns d in [16w,16w+16), lane owns row base+lane.
// Phase 2: one wave-wide pass per row writes its 1024-float one-hot row.
// ---------------------------------------------------------------------------
__global__ __launch_bounds__(256) void vq_outputs_kernel(
    const float* __restrict__ x, const float* __restrict__ emb,
    const int* __restrict__ idxp, float* __restrict__ out,
    int* __restrict__ counts, double* __restrict__ losss) {
    int lane = threadIdx.x & 63;
    int wave = threadIdx.x >> 6;
    int base = blockIdx.x * 64;

    // ---- phase 1: quantized + loss + counts
    int n = base + lane;
    int ix = idxp[n];
    int xoff = (n >> 12) * 262144 + (n & 4095);
    const float4* e4 = (const float4*)(emb + ix * DIM + wave * 16);
    float* qp = out + OUT_Q + xoff;
    double lsum = 0.0;
#pragma unroll
    for (int q = 0; q < 4; ++q) {
        float4 ev = e4[q];
        float evs0 = ev.x, evs1 = ev.y, evs2 = ev.z, evs3 = ev.w;
        int d = wave * 16 + q * 4;
        float x0 = x[xoff + (d + 0) * 4096];
        float x1 = x[xoff + (d + 1) * 4096];
        float x2 = x[xoff + (d + 2) * 4096];
        float x3 = x[xoff + (d + 3) * 4096];
        double d0 = (double)evs0 - x0, d1 = (double)evs1 - x1;
        double d2 = (double)evs2 - x2, d3 = (double)evs3 - x3;
        lsum += d0 * d0 + d1 * d1 + d2 * d2 + d3 * d3;
        qp[(d + 0) * 4096] = evs0;
        qp[(d + 1) * 4096] = evs1;
        qp[(d + 2) * 4096] = evs2;
        qp[(d + 3) * 4096] = evs3;
    }
    if (wave == 0) atomicAdd(&counts[ix], 1);
    for (int off = 32; off > 0; off >>= 1) lsum += __shfl_down(lsum, off);
    if (lane == 0) atomicAdd(losss, lsum);

    // ---- phase 2: encodings one-hot rows (base off by 8B -> float2 stores)
    float* enc = out + OUT_ENC;
    for (int j = 0; j < 16; ++j) {
        int row = base + wave * 16 + j;
        int iv = idxp[row];
        int slot = iv >> 2, r = iv & 3;
        float2 lo, hi;
        lo.x = (slot == lane && r == 0) ? 1.0f : 0.0f;
        lo.y = (slot == lane && r == 1) ? 1.0f : 0.0f;
        hi.x = (slot == lane && r == 2) ? 1.0f : 0.0f;
        hi.y = (slot == lane && r == 3) ? 1.0f : 0.0f;
        float2* dst = (float2*)(enc + (size_t)row * 1024 + lane * 4);
        dst[0] = lo;
        dst[1] = hi;
    }
}

// ---------------------------------------------------------------------------
// Kernel D: perplexity + loss scalars.
// ---------------------------------------------------------------------------
__global__ void vq_finalize_kernel(const int* __restrict__ counts,
                                   const double* __restrict__ losss,
                                   float* __restrict__ out) {
    __shared__ double red[1024];
    int t = threadIdx.x;
    double p = (double)counts[t] / 32768.0;
    red[t] = p * log(p + 1e-10);
    __syncthreads();
    for (int s = 512; s > 0; s >>= 1) {
        if (t < s) red[t] += red[t + s];
        __syncthreads();
    }
    if (t == 0) {
        out[OUT_PERP] = (float)exp(-red[0]);
        out[0] = (float)(losss[0] * (1.25 / 2097152.0));
    }
}

// ---------------------------------------------------------------------------
extern "C" void kernel_launch(void* const* d_in, const int* in_sizes, int n_in,
                              void* d_out, int out_size, void* d_ws,
                              size_t ws_size, hipStream_t stream) {
    (void)in_sizes; (void)n_in; (void)out_size;
    const float* x = (const float*)d_in[0];
    const float* emb = (const float*)d_in[1];
    float* out = (float*)d_out;
    char* ws = (char*)d_ws;

    // K-split factor: 2 if workspace allows (needs ~1.01 MB), else 1 (~664 KB)
    int ks = (ws_size >= 1056784u) ? 2 : 1;

    char* p = ws;
    int* idxp = (int*)p;          p += 131072;
    float* bestA = (float*)p;     p += 131072 * ks;
    float* secA = (float*)p;      p += 131072 * ks;
    int* idxA = (int*)p;          p += 131072 * ks;
    int* flaglist = (int*)p;      p += 131072;
    float* sqnh = (float*)p;      p += 4096;
    int* counts = (int*)p;        p += 4096;
    int* flagcount = (int*)p;     p += 8;   // 4 used + 4 pad (keeps double aligned)
    double* losss = (double*)p;

    // zero: counts + flagcount + losssum (contiguous 4096+8+8)
    hipMemsetAsync(counts, 0, 4096 + 16, stream);

    vq_sqnorm_kernel<<<4, 256, 0, stream>>>(emb, sqnh);
    vq_argmin_kernel<<<512 * ks, 256, 0, stream>>>(x, emb, sqnh, bestA, secA,
                                                   idxA, ks);
    vq_merge_kernel<<<128, 256, 0, stream>>>(bestA, secA, idxA, ks, idxp,
                                             flaglist, flagcount);
    vq_recheck_kernel<<<256, 256, 0, stream>>>(x, emb, flaglist, flagcount,
                                               idxp);
    vq_outputs_kernel<<<512, 256, 0, stream>>>(x, emb, idxp, out, counts,
                                               losss);
    vq_finalize_kernel<<<1, 1024, 0, stream>>>(counts, losss, out);
}